// Round 10
// baseline (124.746 us; speedup 1.0000x reference)
//
#include <hip/hip_runtime.h>

// EdgeCompute v10 — DIAGNOSTIC: v9 bit-identical, grid 512 -> 128.
// Purpose: (a) push kernel duration above the 43us fill dispatches so it
// appears in rocprof top-5 with real counters; (b) clean occupancy A/B:
//   T(128)/T(512) ~ 4x  => wave-latency bound  -> round 11: occupancy
//   T(128)/T(512) ~ 2x  => per-CU pipe bound   -> counters name the pipe
//   out = sigmoid( relu(|x[s]-x[d]| @ W1 + b1) @ W2 + b2 )
// N_EDGES=640000, D_FEAT=128, HID=64.

#define DF 128
#define HID 64
#define AST 136   // halfs per LDS diff row (272 B = 17*16B)

typedef _Float16 half8   __attribute__((ext_vector_type(8)));
typedef _Float16 half4_t __attribute__((ext_vector_type(4)));
typedef float    floatx4 __attribute__((ext_vector_type(4)));

__device__ __forceinline__ float sigmoidf_(float t) {
    return __builtin_amdgcn_rcpf(1.0f + __expf(-t));
}

// pre-pass: x -> f16 (2.56MB, L2-resident), W1 -> f16 transposed [hid][feat]
__global__ void cvt_pre(const float* __restrict__ x, const float* __restrict__ W1,
                        _Float16* __restrict__ xh, _Float16* __restrict__ w1t, int n4)
{
    const int i = blockIdx.x * blockDim.x + threadIdx.x;
    if (i < n4) {
        float4 v = ((const float4*)x)[i];
        half4_t h = { (_Float16)v.x, (_Float16)v.y, (_Float16)v.z, (_Float16)v.w };
        ((half4_t*)xh)[i] = h;
    }
    if (i < DF * HID) {                      // w1t[h*128+f] = W1[f*64+h]
        const int h = i >> 7, f = i & 127;
        w1t[i] = (_Float16)W1[f * HID + h];
    }
}

#define ROW(idv) *(const half8*)(xh + (size_t)(idv) * DF + goff)

#define ISSUE(S, D, sIv, dIv)                                   \
    S##0 = ROW((sIv).x); S##1 = ROW((sIv).y);                   \
    S##2 = ROW((sIv).z); S##3 = ROW((sIv).w);                   \
    D##0 = ROW((dIv).x); D##1 = ROW((dIv).y);                   \
    D##2 = ROW((dIv).z); D##3 = ROW((dIv).w);

#define PROC(t, S, D) {                                                        \
    union { half8 h; uint4 u; } U0, U1, U2, U3;                                \
    U0.h = S##0 - D##0; U1.h = S##1 - D##1;                                    \
    U2.h = S##2 - D##2; U3.h = S##3 - D##3;                                    \
    U0.u.x &= 0x7FFF7FFFu; U0.u.y &= 0x7FFF7FFFu;                              \
    U0.u.z &= 0x7FFF7FFFu; U0.u.w &= 0x7FFF7FFFu;                              \
    U1.u.x &= 0x7FFF7FFFu; U1.u.y &= 0x7FFF7FFFu;                              \
    U1.u.z &= 0x7FFF7FFFu; U1.u.w &= 0x7FFF7FFFu;                              \
    U2.u.x &= 0x7FFF7FFFu; U2.u.y &= 0x7FFF7FFFu;                              \
    U2.u.z &= 0x7FFF7FFFu; U2.u.w &= 0x7FFF7FFFu;                              \
    U3.u.x &= 0x7FFF7FFFu; U3.u.y &= 0x7FFF7FFFu;                              \
    U3.u.z &= 0x7FFF7FFFu; U3.u.w &= 0x7FFF7FFFu;                              \
    *(half8*)(ldsw + ((t) * 16 + q * 4 + 0) * AST + goff) = U0.h;              \
    *(half8*)(ldsw + ((t) * 16 + q * 4 + 1) * AST + goff) = U1.h;              \
    *(half8*)(ldsw + ((t) * 16 + q * 4 + 2) * AST + goff) = U2.h;              \
    *(half8*)(ldsw + ((t) * 16 + q * 4 + 3) * AST + goff) = U3.h; }

__global__ __launch_bounds__(256, 2) void edge_mlp_v10(
    const _Float16* __restrict__ xh, const _Float16* __restrict__ w1t,
    const int* __restrict__ idx,
    const float* __restrict__ b1, const float* __restrict__ W2,
    const float* __restrict__ b2,
    float* __restrict__ out, int n_edges, int ngroups, int gstride)
{
    __shared__ __attribute__((aligned(16))) _Float16 lds_d[4][64 * AST];

    const int tid = threadIdx.x;
    const int L   = tid & 63;
    const int r16 = L & 15;
    const int q   = L >> 4;
    const int wv  = tid >> 6;
    _Float16* const ldsw = &lds_d[wv][0];

    half8 wf[4][4];
#pragma unroll
    for (int mt = 0; mt < 4; ++mt)
#pragma unroll
        for (int kb = 0; kb < 4; ++kb)
            wf[mt][kb] = *(const half8*)(w1t + (size_t)(mt * 16 + r16) * DF + kb * 32 + q * 8);
#pragma unroll
    for (int mt = 0; mt < 4; ++mt)
#pragma unroll
        for (int kb = 0; kb < 4; ++kb)
            asm volatile("" : "+v"(wf[mt][kb]));

    half4_t b1h[4], w2h[4];
#pragma unroll
    for (int mt = 0; mt < 4; ++mt)
#pragma unroll
        for (int r = 0; r < 4; ++r) {
            b1h[mt][r] = (_Float16)b1[mt * 16 + q * 4 + r];
            w2h[mt][r] = (_Float16)W2[mt * 16 + q * 4 + r];
        }
    const float b2v = b2[0];

    const int goff = r16 * 8;
    const int idof = q * 4;

    const int g0 = blockIdx.x;

    int4 sI0, sI1, sI2, sI3, dI0, dI1, dI2, dI3;
    {
        const int eb = g0 * 256 + wv * 64;
        sI0 = *(const int4*)(idx + eb +  0 + idof);
        sI1 = *(const int4*)(idx + eb + 16 + idof);
        sI2 = *(const int4*)(idx + eb + 32 + idof);
        sI3 = *(const int4*)(idx + eb + 48 + idof);
        dI0 = *(const int4*)(idx + n_edges + eb +  0 + idof);
        dI1 = *(const int4*)(idx + n_edges + eb + 16 + idof);
        dI2 = *(const int4*)(idx + n_edges + eb + 32 + idof);
        dI3 = *(const int4*)(idx + n_edges + eb + 48 + idof);
    }

#pragma unroll 1
    for (int g = g0; g < ngroups; g += gstride) {
        half8 sa0, sa1, sa2, sa3, da0, da1, da2, da3;
        half8 sb0, sb1, sb2, sb3, db0, db1, db2, db3;

        ISSUE(sa, da, sI0, dI0);
        ISSUE(sb, db, sI1, dI1);
        PROC(0, sa, da);
        ISSUE(sa, da, sI2, dI2);
        PROC(1, sb, db);
        ISSUE(sb, db, sI3, dI3);
        PROC(2, sa, da);

        int4 sN0, sN1, sN2, sN3, dN0, dN1, dN2, dN3;
        {
            int gn = g + gstride; if (gn >= ngroups) gn = g;
            const int ebn = gn * 256 + wv * 64;
            sN0 = *(const int4*)(idx + ebn +  0 + idof);
            sN1 = *(const int4*)(idx + ebn + 16 + idof);
            sN2 = *(const int4*)(idx + ebn + 32 + idof);
            sN3 = *(const int4*)(idx + ebn + 48 + idof);
            dN0 = *(const int4*)(idx + n_edges + ebn +  0 + idof);
            dN1 = *(const int4*)(idx + n_edges + ebn + 16 + idof);
            dN2 = *(const int4*)(idx + n_edges + ebn + 32 + idof);
            dN3 = *(const int4*)(idx + n_edges + ebn + 48 + idof);
        }

        PROC(3, sb, db);

        floatx4 acc[4][4];
#pragma unroll
        for (int mt = 0; mt < 4; ++mt)
#pragma unroll
            for (int et = 0; et < 4; ++et)
                acc[mt][et] = (floatx4){0.f, 0.f, 0.f, 0.f};
#pragma unroll
        for (int kb = 0; kb < 4; ++kb) {
#pragma unroll
            for (int et = 0; et < 4; ++et) {
                const half8 bf = *(const half8*)(ldsw + (et * 16 + r16) * AST + kb * 32 + q * 8);
                acc[0][et] = __builtin_amdgcn_mfma_f32_16x16x32_f16(wf[0][kb], bf, acc[0][et], 0, 0, 0);
                acc[1][et] = __builtin_amdgcn_mfma_f32_16x16x32_f16(wf[1][kb], bf, acc[1][et], 0, 0, 0);
                acc[2][et] = __builtin_amdgcn_mfma_f32_16x16x32_f16(wf[2][kb], bf, acc[2][et], 0, 0, 0);
                acc[3][et] = __builtin_amdgcn_mfma_f32_16x16x32_f16(wf[3][kb], bf, acc[3][et], 0, 0, 0);
            }
        }

        sI0 = sN0; sI1 = sN1; sI2 = sN2; sI3 = sN3;
        dI0 = dN0; dI1 = dN1; dI2 = dN2; dI3 = dN3;

#pragma unroll
        for (int et = 0; et < 4; ++et) {
            float part = 0.f;
#pragma unroll
            for (int mt = 0; mt < 4; ++mt)
#pragma unroll
                for (int r = 0; r < 4; ++r)
                    part = fmaf(fmaxf(acc[mt][et][r] + (float)b1h[mt][r], 0.f),
                                (float)w2h[mt][r], part);
            part += __shfl_xor(part, 16, 64);
            part += __shfl_xor(part, 32, 64);
            if (L < 16)
                out[g * 256 + wv * 64 + et * 16 + L] = sigmoidf_(part + b2v);
        }
    }
}

// fallback / tail
__global__ void edge_naive(const float* __restrict__ x, const int* __restrict__ idx,
                           const float* __restrict__ W1, const float* __restrict__ b1,
                           const float* __restrict__ W2, const float* __restrict__ b2,
                           float* __restrict__ out, int n_edges, int start)
{
    int e = start + blockIdx.x * blockDim.x + threadIdx.x;
    if (e >= n_edges) return;
    int s = idx[e], d = idx[n_edges + e];
    float t = b2[0];
    for (int j = 0; j < HID; ++j) {
        float h = b1[j];
        for (int k = 0; k < DF; ++k)
            h = fmaf(fabsf(x[(size_t)s * DF + k] - x[(size_t)d * DF + k]), W1[(size_t)k * HID + j], h);
        t = fmaf(fmaxf(h, 0.f), W2[j], t);
    }
    out[e] = sigmoidf_(t);
}

extern "C" void kernel_launch(void* const* d_in, const int* in_sizes, int n_in,
                              void* d_out, int out_size, void* d_ws, size_t ws_size,
                              hipStream_t stream) {
    const float* x   = (const float*)d_in[0];
    const int*   idx = (const int*)d_in[1];
    const float* W1  = (const float*)d_in[2];
    const float* b1  = (const float*)d_in[3];
    const float* W2  = (const float*)d_in[4];
    const float* b2  = (const float*)d_in[5];
    float* out = (float*)d_out;

    const int n_edges = in_sizes[1] / 2;      // indices is [2, n_edges]
    const int n_x     = in_sizes[0];
    const int ngroups = n_edges / 256;        // 256 edges per block-tile
    const int rem     = n_edges - ngroups * 256;

    const size_t xh_bytes  = ((size_t)n_x * sizeof(_Float16) + 255) & ~(size_t)255;
    const size_t w1t_bytes = (size_t)DF * HID * sizeof(_Float16);
    const bool ok = (ws_size >= xh_bytes + w1t_bytes) && (n_x % 4 == 0);

    if (ok && ngroups > 0) {
        _Float16* xh  = (_Float16*)d_ws;
        _Float16* w1t = (_Float16*)((char*)d_ws + xh_bytes);
        const int n4 = n_x / 4;
        cvt_pre<<<(n4 + 255) / 256, 256, 0, stream>>>(x, W1, xh, w1t, n4);

        // DIAGNOSTIC grid: 128 blocks (half the CUs, 1 block/CU) so the main
        // kernel exceeds the 43us fill dispatches and surfaces in rocprof
        // top-5 with real counters; also a clean occupancy-scaling A/B vs
        // round 9's grid=512.
        const int grid = ngroups < 128 ? ngroups : 128;
        edge_mlp_v10<<<grid, 256, 0, stream>>>(xh, w1t, idx, b1, W2, b2,
                                               out, n_edges, ngroups, grid);
        if (rem > 0)
            edge_naive<<<(rem + 63) / 64, 64, 0, stream>>>(x, idx, W1, b1, W2, b2,
                                                           out, n_edges, ngroups * 256);
    } else {
        edge_naive<<<(n_edges + 63) / 64, 64, 0, stream>>>(x, idx, W1, b1, W2, b2,
                                                           out, n_edges, 0);
    }
}

// Round 12
// 103.687 us; speedup vs baseline: 1.2031x; 1.2031x over previous
//
#include <hip/hip_runtime.h>

// EdgeCompute v12: v9 (f16, known-good) + L1-BYPASS gather via device-scope
// relaxed atomic loads (sc0).  out = sigmoid( relu(|x[s]-x[d]|@W1+b1)@W2+b2 )
// N_EDGES=640000, D_FEAT=128, HID=64.
//
// Round-10/11 model: gather rate 17.6 B/cyc/CU ~= 0.28 lines/cyc ~= 64 MSHRs
// / 200cyc L2 latency -> L1 miss-tracking occupancy is the bound, not BW.
// fp8 (halve lines) failed accuracy (0.043 > 0.0196 threshold; f16=0.0039).
// v12 experiment: __hip_atomic_load(relaxed, AGENT) on x rows -> global_load
// with sc0 (L1 bypass / no allocate), compiler-managed vmcnt (no asm hazard).
// Rows load as 2x8B per lane (atomic max width) instead of 1x16B.
// Everything else bit-identical to v9: 64-edge wave tiles, lane-contiguous
// rows (4 rows/instr), per-wave LDS transpose (no barriers), W1^T f16 in 64
// VGPRs, transposed MFMA D[hid][edge], 2-shfl epilogue, id int4 prefetch,
// grid 512 (2 blocks/CU).

#define DF 128
#define HID 64
#define AST 136   // halfs per LDS diff row (272 B = 17*16B)

typedef _Float16 half8   __attribute__((ext_vector_type(8)));
typedef _Float16 half4_t __attribute__((ext_vector_type(4)));
typedef float    floatx4 __attribute__((ext_vector_type(4)));
typedef unsigned long long u64;

__device__ __forceinline__ float sigmoidf_(float t) {
    return __builtin_amdgcn_rcpf(1.0f + __expf(-t));
}

// pre-pass: x -> f16 (2.56MB, L2-resident), W1 -> f16 transposed [hid][feat]
__global__ void cvt_pre(const float* __restrict__ x, const float* __restrict__ W1,
                        _Float16* __restrict__ xh, _Float16* __restrict__ w1t, int n4)
{
    const int i = blockIdx.x * blockDim.x + threadIdx.x;
    if (i < n4) {
        float4 v = ((const float4*)x)[i];
        half4_t h = { (_Float16)v.x, (_Float16)v.y, (_Float16)v.z, (_Float16)v.w };
        ((half4_t*)xh)[i] = h;
    }
    if (i < DF * HID) {                      // w1t[h*128+f] = W1[f*64+h]
        const int h = i >> 7, f = i & 127;
        w1t[i] = (_Float16)W1[f * HID + h];
    }
}

// L1-bypass row chunk load: 16B of row idv at halfs-offset goff, as 2x8B
// device-scope relaxed atomic loads (emit global_load_dwordx2 sc0).
#define ROWA(idv, LO, HI) {                                                    \
    const u64* _p = (const u64*)(xh + (size_t)(idv) * DF + goff);              \
    LO = __hip_atomic_load(_p,     __ATOMIC_RELAXED, __HIP_MEMORY_SCOPE_AGENT);\
    HI = __hip_atomic_load(_p + 1, __ATOMIC_RELAXED, __HIP_MEMORY_SCOPE_AGENT);}

#define ISSUE(S, D, sIv, dIv)                        \
    ROWA((sIv).x, S##0l, S##0h) ROWA((sIv).y, S##1l, S##1h) \
    ROWA((sIv).z, S##2l, S##2h) ROWA((sIv).w, S##3l, S##3h) \
    ROWA((dIv).x, D##0l, D##0h) ROWA((dIv).y, D##1l, D##1h) \
    ROWA((dIv).z, D##2l, D##2h) ROWA((dIv).w, D##3l, D##3h)

#define MK8(lo_, hi_) ({ union { u64 u[2]; half8 h; } _m; _m.u[0] = (lo_); _m.u[1] = (hi_); _m.h; })

// |s - d| -> LDS rows (t*16 + q*4 + p), chunk r16
#define PROC(t, S, D) {                                                        \
    union { half8 h; uint4 u; } U0, U1, U2, U3;                                \
    U0.h = MK8(S##0l, S##0h) - MK8(D##0l, D##0h);                              \
    U1.h = MK8(S##1l, S##1h) - MK8(D##1l, D##1h);                              \
    U2.h = MK8(S##2l, S##2h) - MK8(D##2l, D##2h);                              \
    U3.h = MK8(S##3l, S##3h) - MK8(D##3l, D##3h);                              \
    U0.u.x &= 0x7FFF7FFFu; U0.u.y &= 0x7FFF7FFFu;                              \
    U0.u.z &= 0x7FFF7FFFu; U0.u.w &= 0x7FFF7FFFu;                              \
    U1.u.x &= 0x7FFF7FFFu; U1.u.y &= 0x7FFF7FFFu;                              \
    U1.u.z &= 0x7FFF7FFFu; U1.u.w &= 0x7FFF7FFFu;                              \
    U2.u.x &= 0x7FFF7FFFu; U2.u.y &= 0x7FFF7FFFu;                              \
    U2.u.z &= 0x7FFF7FFFu; U2.u.w &= 0x7FFF7FFFu;                              \
    U3.u.x &= 0x7FFF7FFFu; U3.u.y &= 0x7FFF7FFFu;                              \
    U3.u.z &= 0x7FFF7FFFu; U3.u.w &= 0x7FFF7FFFu;                              \
    *(half8*)(ldsw + ((t) * 16 + q * 4 + 0) * AST + goff) = U0.h;              \
    *(half8*)(ldsw + ((t) * 16 + q * 4 + 1) * AST + goff) = U1.h;              \
    *(half8*)(ldsw + ((t) * 16 + q * 4 + 2) * AST + goff) = U2.h;              \
    *(half8*)(ldsw + ((t) * 16 + q * 4 + 3) * AST + goff) = U3.h; }

__global__ __launch_bounds__(256, 2) void edge_mlp_v12(
    const _Float16* __restrict__ xh, const _Float16* __restrict__ w1t,
    const int* __restrict__ idx,
    const float* __restrict__ b1, const float* __restrict__ W2,
    const float* __restrict__ b2,
    float* __restrict__ out, int n_edges, int ngroups, int gstride)
{
    // per-wave diff tile: [64 edges][128 k (+8 pad)] f16
    __shared__ __attribute__((aligned(16))) _Float16 lds_d[4][64 * AST];

    const int tid = threadIdx.x;
    const int L   = tid & 63;
    const int r16 = L & 15;                 // gather: 16B chunk; frag-read: edge
    const int q   = L >> 4;                 // gather: row-in-quartet; frag: quad
    const int wv  = tid >> 6;
    _Float16* const ldsw = &lds_d[wv][0];

    // ---- A fragments: W1^T [hid=mt*16+r16][k=kb*32+q*8+j] (64 VGPRs) ----
    half8 wf[4][4];
#pragma unroll
    for (int mt = 0; mt < 4; ++mt)
#pragma unroll
        for (int kb = 0; kb < 4; ++kb)
            wf[mt][kb] = *(const half8*)(w1t + (size_t)(mt * 16 + r16) * DF + kb * 32 + q * 8);
#pragma unroll
    for (int mt = 0; mt < 4; ++mt)
#pragma unroll
        for (int kb = 0; kb < 4; ++kb)
            asm volatile("" : "+v"(wf[mt][kb]));

    // epilogue constants at hid = mt*16 + q*4 + r
    half4_t b1h[4], w2h[4];
#pragma unroll
    for (int mt = 0; mt < 4; ++mt)
#pragma unroll
        for (int r = 0; r < 4; ++r) {
            b1h[mt][r] = (_Float16)b1[mt * 16 + q * 4 + r];
            w2h[mt][r] = (_Float16)W2[mt * 16 + q * 4 + r];
        }
    const float b2v = b2[0];

    const int goff = r16 * 8;    // halfs offset of this lane's 16B chunk
    const int idof = q * 4;      // this lane's 4 contiguous ids per 16-edge batch

    const int g0 = blockIdx.x;

    int4 sI0, sI1, sI2, sI3, dI0, dI1, dI2, dI3;
    {
        const int eb = g0 * 256 + wv * 64;
        sI0 = *(const int4*)(idx + eb +  0 + idof);
        sI1 = *(const int4*)(idx + eb + 16 + idof);
        sI2 = *(const int4*)(idx + eb + 32 + idof);
        sI3 = *(const int4*)(idx + eb + 48 + idof);
        dI0 = *(const int4*)(idx + n_edges + eb +  0 + idof);
        dI1 = *(const int4*)(idx + n_edges + eb + 16 + idof);
        dI2 = *(const int4*)(idx + n_edges + eb + 32 + idof);
        dI3 = *(const int4*)(idx + n_edges + eb + 48 + idof);
    }

#pragma unroll 1
    for (int g = g0; g < ngroups; g += gstride) {
        u64 sa0l, sa0h, sa1l, sa1h, sa2l, sa2h, sa3l, sa3h;
        u64 da0l, da0h, da1l, da1h, da2l, da2h, da3l, da3h;
        u64 sb0l, sb0h, sb1l, sb1h, sb2l, sb2h, sb3l, sb3h;
        u64 db0l, db0h, db1l, db1h, db2l, db2h, db3l, db3h;

        // batched gather: 1.5 batches in flight (all sc0 / L1-bypass)
        ISSUE(sa, da, sI0, dI0);
        ISSUE(sb, db, sI1, dI1);
        PROC(0, sa, da);
        ISSUE(sa, da, sI2, dI2);
        PROC(1, sb, db);
        ISSUE(sb, db, sI3, dI3);
        PROC(2, sa, da);

        // prefetch ids for the NEXT tile (normal cached loads)
        int4 sN0, sN1, sN2, sN3, dN0, dN1, dN2, dN3;
        {
            int gn = g + gstride; if (gn >= ngroups) gn = g;
            const int ebn = gn * 256 + wv * 64;
            sN0 = *(const int4*)(idx + ebn +  0 + idof);
            sN1 = *(const int4*)(idx + ebn + 16 + idof);
            sN2 = *(const int4*)(idx + ebn + 32 + idof);
            sN3 = *(const int4*)(idx + ebn + 48 + idof);
            dN0 = *(const int4*)(idx + n_edges + ebn +  0 + idof);
            dN1 = *(const int4*)(idx + n_edges + ebn + 16 + idof);
            dN2 = *(const int4*)(idx + n_edges + ebn + 32 + idof);
            dN3 = *(const int4*)(idx + n_edges + ebn + 48 + idof);
        }

        PROC(3, sb, db);

        // ---- MFMA: D[hid 64][edge 64] = W1^T * diff ----
        floatx4 acc[4][4];
#pragma unroll
        for (int mt = 0; mt < 4; ++mt)
#pragma unroll
            for (int et = 0; et < 4; ++et)
                acc[mt][et] = (floatx4){0.f, 0.f, 0.f, 0.f};
#pragma unroll
        for (int kb = 0; kb < 4; ++kb) {
#pragma unroll
            for (int et = 0; et < 4; ++et) {
                const half8 bf = *(const half8*)(ldsw + (et * 16 + r16) * AST + kb * 32 + q * 8);
                acc[0][et] = __builtin_amdgcn_mfma_f32_16x16x32_f16(wf[0][kb], bf, acc[0][et], 0, 0, 0);
                acc[1][et] = __builtin_amdgcn_mfma_f32_16x16x32_f16(wf[1][kb], bf, acc[1][et], 0, 0, 0);
                acc[2][et] = __builtin_amdgcn_mfma_f32_16x16x32_f16(wf[2][kb], bf, acc[2][et], 0, 0, 0);
                acc[3][et] = __builtin_amdgcn_mfma_f32_16x16x32_f16(wf[3][kb], bf, acc[3][et], 0, 0, 0);
            }
        }

        sI0 = sN0; sI1 = sN1; sI2 = sN2; sI3 = sN3;
        dI0 = dN0; dI1 = dN1; dI2 = dN2; dI3 = dN3;

        // ---- epilogue: relu -> *W2 -> reduce over quads -> sigmoid ----
#pragma unroll
        for (int et = 0; et < 4; ++et) {
            float part = 0.f;
#pragma unroll
            for (int mt = 0; mt < 4; ++mt)
#pragma unroll
                for (int r = 0; r < 4; ++r)
                    part = fmaf(fmaxf(acc[mt][et][r] + (float)b1h[mt][r], 0.f),
                                (float)w2h[mt][r], part);
            part += __shfl_xor(part, 16, 64);
            part += __shfl_xor(part, 32, 64);
            if (L < 16)
                out[g * 256 + wv * 64 + et * 16 + L] = sigmoidf_(part + b2v);
        }
    }
}

// fallback / tail
__global__ void edge_naive(const float* __restrict__ x, const int* __restrict__ idx,
                           const float* __restrict__ W1, const float* __restrict__ b1,
                           const float* __restrict__ W2, const float* __restrict__ b2,
                           float* __restrict__ out, int n_edges, int start)
{
    int e = start + blockIdx.x * blockDim.x + threadIdx.x;
    if (e >= n_edges) return;
    int s = idx[e], d = idx[n_edges + e];
    float t = b2[0];
    for (int j = 0; j < HID; ++j) {
        float h = b1[j];
        for (int k = 0; k < DF; ++k)
            h = fmaf(fabsf(x[(size_t)s * DF + k] - x[(size_t)d * DF + k]), W1[(size_t)k * HID + j], h);
        t = fmaf(fmaxf(h, 0.f), W2[j], t);
    }
    out[e] = sigmoidf_(t);
}

extern "C" void kernel_launch(void* const* d_in, const int* in_sizes, int n_in,
                              void* d_out, int out_size, void* d_ws, size_t ws_size,
                              hipStream_t stream) {
    const float* x   = (const float*)d_in[0];
    const int*   idx = (const int*)d_in[1];
    const float* W1  = (const float*)d_in[2];
    const float* b1  = (const float*)d_in[3];
    const float* W2  = (const float*)d_in[4];
    const float* b2  = (const float*)d_in[5];
    float* out = (float*)d_out;

    const int n_edges = in_sizes[1] / 2;      // indices is [2, n_edges]
    const int n_x     = in_sizes[0];
    const int ngroups = n_edges / 256;        // 256 edges per block-tile
    const int rem     = n_edges - ngroups * 256;

    const size_t xh_bytes  = ((size_t)n_x * sizeof(_Float16) + 255) & ~(size_t)255;
    const size_t w1t_bytes = (size_t)DF * HID * sizeof(_Float16);
    const bool ok = (ws_size >= xh_bytes + w1t_bytes) && (n_x % 4 == 0);

    if (ok && ngroups > 0) {
        _Float16* xh  = (_Float16*)d_ws;
        _Float16* w1t = (_Float16*)((char*)d_ws + xh_bytes);
        const int n4 = n_x / 4;
        cvt_pre<<<(n4 + 255) / 256, 256, 0, stream>>>(x, W1, xh, w1t, n4);

        const int grid = ngroups < 512 ? ngroups : 512;   // 2 blocks/CU
        edge_mlp_v12<<<grid, 256, 0, stream>>>(xh, w1t, idx, b1, W2, b2,
                                               out, n_edges, ngroups, grid);
        if (rem > 0)
            edge_naive<<<(rem + 63) / 64, 64, 0, stream>>>(x, idx, W1, b1, W2, b2,
                                                           out, n_edges, ngroups * 256);
    } else {
        edge_naive<<<(n_edges + 63) / 64, 64, 0, stream>>>(x, idx, W1, b1, W2, b2,
                                                           out, n_edges, 0);
    }
}

// Round 13
// 95.342 us; speedup vs baseline: 1.3084x; 1.0875x over previous
//
#include <hip/hip_runtime.h>

// EdgeCompute v13 = v9 revert (best known: bench 94.9us, kernel ~33us).
//   out = sigmoid( relu(|x[s]-x[d]| @ W1 + b1) @ W2 + b2 )
// N_EDGES=640000, D_FEAT=128, HID=64.
//
// Final model (r10 A/B + r12 bypass probe): kernel sits AT the per-CU
// scattered-line service wall: 5.1M gathered 64B lines (f16 rows, 100%
// consumed) / 256 CU x ~3.9 cyc/line ~= 33us. Levers exhausted: fp8 bytes
// (accuracy fail), L1 bypass (regressed — request-count bound), occupancy
// x2 (neutral), tile x4 (neutral), 16B/lane max width (in use). f16 is the
// minimum precision passing the 0.0196 absmax threshold (0.0039, 5x margin).

#define DF 128
#define HID 64
#define AST 136   // halfs per LDS diff row (272 B = 17*16B)

typedef _Float16 half8   __attribute__((ext_vector_type(8)));
typedef _Float16 half4_t __attribute__((ext_vector_type(4)));
typedef float    floatx4 __attribute__((ext_vector_type(4)));

__device__ __forceinline__ float sigmoidf_(float t) {
    return __builtin_amdgcn_rcpf(1.0f + __expf(-t));
}

// pre-pass: x -> f16 (2.56MB, L2-resident), W1 -> f16 transposed [hid][feat]
__global__ void cvt_pre(const float* __restrict__ x, const float* __restrict__ W1,
                        _Float16* __restrict__ xh, _Float16* __restrict__ w1t, int n4)
{
    const int i = blockIdx.x * blockDim.x + threadIdx.x;
    if (i < n4) {
        float4 v = ((const float4*)x)[i];
        half4_t h = { (_Float16)v.x, (_Float16)v.y, (_Float16)v.z, (_Float16)v.w };
        ((half4_t*)xh)[i] = h;
    }
    if (i < DF * HID) {                      // w1t[h*128+f] = W1[f*64+h]
        const int h = i >> 7, f = i & 127;
        w1t[i] = (_Float16)W1[f * HID + h];
    }
}

#define ROW(idv) *(const half8*)(xh + (size_t)(idv) * DF + goff)

#define ISSUE(S, D, sIv, dIv)                                   \
    S##0 = ROW((sIv).x); S##1 = ROW((sIv).y);                   \
    S##2 = ROW((sIv).z); S##3 = ROW((sIv).w);                   \
    D##0 = ROW((dIv).x); D##1 = ROW((dIv).y);                   \
    D##2 = ROW((dIv).z); D##3 = ROW((dIv).w);

#define PROC(t, S, D) {                                                        \
    union { half8 h; uint4 u; } U0, U1, U2, U3;                                \
    U0.h = S##0 - D##0; U1.h = S##1 - D##1;                                    \
    U2.h = S##2 - D##2; U3.h = S##3 - D##3;                                    \
    U0.u.x &= 0x7FFF7FFFu; U0.u.y &= 0x7FFF7FFFu;                              \
    U0.u.z &= 0x7FFF7FFFu; U0.u.w &= 0x7FFF7FFFu;                              \
    U1.u.x &= 0x7FFF7FFFu; U1.u.y &= 0x7FFF7FFFu;                              \
    U1.u.z &= 0x7FFF7FFFu; U1.u.w &= 0x7FFF7FFFu;                              \
    U2.u.x &= 0x7FFF7FFFu; U2.u.y &= 0x7FFF7FFFu;                              \
    U2.u.z &= 0x7FFF7FFFu; U2.u.w &= 0x7FFF7FFFu;                              \
    U3.u.x &= 0x7FFF7FFFu; U3.u.y &= 0x7FFF7FFFu;                              \
    U3.u.z &= 0x7FFF7FFFu; U3.u.w &= 0x7FFF7FFFu;                              \
    *(half8*)(ldsw + ((t) * 16 + q * 4 + 0) * AST + goff) = U0.h;              \
    *(half8*)(ldsw + ((t) * 16 + q * 4 + 1) * AST + goff) = U1.h;              \
    *(half8*)(ldsw + ((t) * 16 + q * 4 + 2) * AST + goff) = U2.h;              \
    *(half8*)(ldsw + ((t) * 16 + q * 4 + 3) * AST + goff) = U3.h; }

__global__ __launch_bounds__(256, 2) void edge_mlp_v13(
    const _Float16* __restrict__ xh, const _Float16* __restrict__ w1t,
    const int* __restrict__ idx,
    const float* __restrict__ b1, const float* __restrict__ W2,
    const float* __restrict__ b2,
    float* __restrict__ out, int n_edges, int ngroups, int gstride)
{
    // per-wave diff tile: [64 edges][128 k (+8 pad)] f16
    __shared__ __attribute__((aligned(16))) _Float16 lds_d[4][64 * AST];

    const int tid = threadIdx.x;
    const int L   = tid & 63;
    const int r16 = L & 15;                 // gather: 16B chunk; frag-read: edge
    const int q   = L >> 4;                 // gather: row-in-quartet; frag: quad
    const int wv  = tid >> 6;
    _Float16* const ldsw = &lds_d[wv][0];

    // ---- A fragments: W1^T [hid=mt*16+r16][k=kb*32+q*8+j] (64 VGPRs) ----
    half8 wf[4][4];
#pragma unroll
    for (int mt = 0; mt < 4; ++mt)
#pragma unroll
        for (int kb = 0; kb < 4; ++kb)
            wf[mt][kb] = *(const half8*)(w1t + (size_t)(mt * 16 + r16) * DF + kb * 32 + q * 8);
#pragma unroll
    for (int mt = 0; mt < 4; ++mt)
#pragma unroll
        for (int kb = 0; kb < 4; ++kb)
            asm volatile("" : "+v"(wf[mt][kb]));

    // epilogue constants at hid = mt*16 + q*4 + r
    half4_t b1h[4], w2h[4];
#pragma unroll
    for (int mt = 0; mt < 4; ++mt)
#pragma unroll
        for (int r = 0; r < 4; ++r) {
            b1h[mt][r] = (_Float16)b1[mt * 16 + q * 4 + r];
            w2h[mt][r] = (_Float16)W2[mt * 16 + q * 4 + r];
        }
    const float b2v = b2[0];

    const int goff = r16 * 8;    // halfs offset of this lane's 16B chunk
    const int idof = q * 4;      // this lane's 4 contiguous ids per 16-edge batch

    const int g0 = blockIdx.x;

    int4 sI0, sI1, sI2, sI3, dI0, dI1, dI2, dI3;
    {
        const int eb = g0 * 256 + wv * 64;
        sI0 = *(const int4*)(idx + eb +  0 + idof);
        sI1 = *(const int4*)(idx + eb + 16 + idof);
        sI2 = *(const int4*)(idx + eb + 32 + idof);
        sI3 = *(const int4*)(idx + eb + 48 + idof);
        dI0 = *(const int4*)(idx + n_edges + eb +  0 + idof);
        dI1 = *(const int4*)(idx + n_edges + eb + 16 + idof);
        dI2 = *(const int4*)(idx + n_edges + eb + 32 + idof);
        dI3 = *(const int4*)(idx + n_edges + eb + 48 + idof);
    }

#pragma unroll 1
    for (int g = g0; g < ngroups; g += gstride) {
        half8 sa0, sa1, sa2, sa3, da0, da1, da2, da3;   // buffer A
        half8 sb0, sb1, sb2, sb3, db0, db1, db2, db3;   // buffer B

        // batched gather: 1.5 batches in flight
        ISSUE(sa, da, sI0, dI0);
        ISSUE(sb, db, sI1, dI1);
        PROC(0, sa, da);
        ISSUE(sa, da, sI2, dI2);
        PROC(1, sb, db);
        ISSUE(sb, db, sI3, dI3);
        PROC(2, sa, da);

        // prefetch ids for the NEXT tile (arrive during MFMA/epilogue)
        int4 sN0, sN1, sN2, sN3, dN0, dN1, dN2, dN3;
        {
            int gn = g + gstride; if (gn >= ngroups) gn = g;
            const int ebn = gn * 256 + wv * 64;
            sN0 = *(const int4*)(idx + ebn +  0 + idof);
            sN1 = *(const int4*)(idx + ebn + 16 + idof);
            sN2 = *(const int4*)(idx + ebn + 32 + idof);
            sN3 = *(const int4*)(idx + ebn + 48 + idof);
            dN0 = *(const int4*)(idx + n_edges + ebn +  0 + idof);
            dN1 = *(const int4*)(idx + n_edges + ebn + 16 + idof);
            dN2 = *(const int4*)(idx + n_edges + ebn + 32 + idof);
            dN3 = *(const int4*)(idx + n_edges + ebn + 48 + idof);
        }

        PROC(3, sb, db);

        // ---- MFMA: D[hid 64][edge 64] = W1^T * diff ----
        floatx4 acc[4][4];
#pragma unroll
        for (int mt = 0; mt < 4; ++mt)
#pragma unroll
            for (int et = 0; et < 4; ++et)
                acc[mt][et] = (floatx4){0.f, 0.f, 0.f, 0.f};
#pragma unroll
        for (int kb = 0; kb < 4; ++kb) {
#pragma unroll
            for (int et = 0; et < 4; ++et) {
                const half8 bf = *(const half8*)(ldsw + (et * 16 + r16) * AST + kb * 32 + q * 8);
                acc[0][et] = __builtin_amdgcn_mfma_f32_16x16x32_f16(wf[0][kb], bf, acc[0][et], 0, 0, 0);
                acc[1][et] = __builtin_amdgcn_mfma_f32_16x16x32_f16(wf[1][kb], bf, acc[1][et], 0, 0, 0);
                acc[2][et] = __builtin_amdgcn_mfma_f32_16x16x32_f16(wf[2][kb], bf, acc[2][et], 0, 0, 0);
                acc[3][et] = __builtin_amdgcn_mfma_f32_16x16x32_f16(wf[3][kb], bf, acc[3][et], 0, 0, 0);
            }
        }

        sI0 = sN0; sI1 = sN1; sI2 = sN2; sI3 = sN3;
        dI0 = dN0; dI1 = dN1; dI2 = dN2; dI3 = dN3;

        // ---- epilogue: relu -> *W2 -> reduce over quads -> sigmoid ----
#pragma unroll
        for (int et = 0; et < 4; ++et) {
            float part = 0.f;
#pragma unroll
            for (int mt = 0; mt < 4; ++mt)
#pragma unroll
                for (int r = 0; r < 4; ++r)
                    part = fmaf(fmaxf(acc[mt][et][r] + (float)b1h[mt][r], 0.f),
                                (float)w2h[mt][r], part);
            part += __shfl_xor(part, 16, 64);
            part += __shfl_xor(part, 32, 64);
            if (L < 16)
                out[g * 256 + wv * 64 + et * 16 + L] = sigmoidf_(part + b2v);
        }
    }
}

// fallback / tail
__global__ void edge_naive(const float* __restrict__ x, const int* __restrict__ idx,
                           const float* __restrict__ W1, const float* __restrict__ b1,
                           const float* __restrict__ W2, const float* __restrict__ b2,
                           float* __restrict__ out, int n_edges, int start)
{
    int e = start + blockIdx.x * blockDim.x + threadIdx.x;
    if (e >= n_edges) return;
    int s = idx[e], d = idx[n_edges + e];
    float t = b2[0];
    for (int j = 0; j < HID; ++j) {
        float h = b1[j];
        for (int k = 0; k < DF; ++k)
            h = fmaf(fabsf(x[(size_t)s * DF + k] - x[(size_t)d * DF + k]), W1[(size_t)k * HID + j], h);
        t = fmaf(fmaxf(h, 0.f), W2[j], t);
    }
    out[e] = sigmoidf_(t);
}

extern "C" void kernel_launch(void* const* d_in, const int* in_sizes, int n_in,
                              void* d_out, int out_size, void* d_ws, size_t ws_size,
                              hipStream_t stream) {
    const float* x   = (const float*)d_in[0];
    const int*   idx = (const int*)d_in[1];
    const float* W1  = (const float*)d_in[2];
    const float* b1  = (const float*)d_in[3];
    const float* W2  = (const float*)d_in[4];
    const float* b2  = (const float*)d_in[5];
    float* out = (float*)d_out;

    const int n_edges = in_sizes[1] / 2;      // indices is [2, n_edges]
    const int n_x     = in_sizes[0];
    const int ngroups = n_edges / 256;        // 256 edges per block-tile
    const int rem     = n_edges - ngroups * 256;

    const size_t xh_bytes  = ((size_t)n_x * sizeof(_Float16) + 255) & ~(size_t)255;
    const size_t w1t_bytes = (size_t)DF * HID * sizeof(_Float16);
    const bool ok = (ws_size >= xh_bytes + w1t_bytes) && (n_x % 4 == 0);

    if (ok && ngroups > 0) {
        _Float16* xh  = (_Float16*)d_ws;
        _Float16* w1t = (_Float16*)((char*)d_ws + xh_bytes);
        const int n4 = n_x / 4;
        cvt_pre<<<(n4 + 255) / 256, 256, 0, stream>>>(x, W1, xh, w1t, n4);

        const int grid = ngroups < 512 ? ngroups : 512;   // 2 blocks/CU (LDS-capped)
        edge_mlp_v13<<<grid, 256, 0, stream>>>(xh, w1t, idx, b1, W2, b2,
                                               out, n_edges, ngroups, grid);
        if (rem > 0)
            edge_naive<<<(rem + 63) / 64, 64, 0, stream>>>(x, idx, W1, b1, W2, b2,
                                                           out, n_edges, ngroups * 256);
    } else {
        edge_naive<<<(n_edges + 63) / 64, 64, 0, stream>>>(x, idx, W1, b1, W2, b2,
                                                           out, n_edges, 0);
    }
}